// Round 10
// baseline (302.999 us; speedup 1.0000x reference)
//
#include <hip/hip_runtime.h>

constexpr int HID  = 20;
constexpr int NEXP = 16;
constexpr int CAP  = 20480;       // per-expert list capacity (avg 16384, sigma~124)
constexpr int NS   = 2;           // samples per thread in eval (consecutive slots)
constexpr int SPB  = 256 * NS;    // 512 samples per eval block
constexpr int BPE  = CAP / SPB;   // 40 chunk slots per expert
constexpr int ROUNDS = 4;         // samples per lane in bucket kernel
constexpr int GSTRIDE = 16;       // ints between gcnt counters -> one 64B line each

// LDS float offsets for the single staged expert (all 16B-aligned)
constexpr int OFF_W1 = 0;     // [2][20]
constexpr int OFF_B1 = 40;    // [20]
constexpr int OFF_W2 = 60;    // [20][20]
constexpr int OFF_B2 = 460;
constexpr int OFF_W3 = 480;
constexpr int OFF_B3 = 880;
constexpr int OFF_W4 = 900;
constexpr int OFF_B4 = 1300;
constexpr int OFF_W5 = 1320;  // [20]
constexpr int OFF_B5 = 1340;  // [1]
constexpr int EFLOATS = 1344;

__device__ __forceinline__ float silu(float v) {
    float e = __expf(-v);
    return v * __builtin_amdgcn_rcpf(1.0f + e);
}

// region index per reference _region_mask: first cell lower bound inclusive,
// upper bounds inclusive, outside [-4,4] (or NaN) -> -1 (=> output 0)
__device__ __forceinline__ int cell_idx(float v) {
    if (!(v >= -4.0f))  return -1;   // also catches NaN
    if (v <= -0.674f)   return 0;
    if (v <= 0.0f)      return 1;
    if (v <= 0.674f)    return 2;
    if (v <= 4.0f)      return 3;
    return -1;
}

// ---------------- kernel 1: bucket samples into per-expert lists ----------------
// (unchanged — measured ~1.8us incl. memset)
__global__ __launch_bounds__(256) void bucket_kernel(
    const float* __restrict__ x, int n_total,
    int* __restrict__ gcnt, int* __restrict__ lists,
    float* __restrict__ out)
{
    __shared__ int wcnt[4][NEXP];
    __shared__ int wbase[4][NEXP];

    const int tid  = threadIdx.x;
    const int lane = tid & 63;
    const int wv   = tid >> 6;
    const int base = blockIdx.x * (4 * ROUNDS * 64) + wv * (ROUNDS * 64);
    const unsigned long long lmask = (1ull << lane) - 1ull;
    const float2* x2 = reinterpret_cast<const float2*>(x);

    unsigned int epack = 0;
    int cnt[NEXP];
    #pragma unroll
    for (int k = 0; k < NEXP; ++k) cnt[k] = 0;

    #pragma unroll
    for (int r = 0; r < ROUNDS; ++r) {
        const int n = base + r * 64 + lane;
        int e = 17;
        if (n < n_total) {
            const float2 xv = x2[n];
            const int c = cell_idx(xv.x), rr = cell_idx(xv.y);
            e = ((c | rr) >= 0) ? (c * 4 + rr) : 16;
        }
        epack |= (unsigned)e << (r * 8);
        #pragma unroll
        for (int k = 0; k < NEXP; ++k)
            cnt[k] += (int)__popcll(__ballot(e == k));
    }

    if (lane == 0) {
        #pragma unroll
        for (int k = 0; k < NEXP; ++k) wcnt[wv][k] = cnt[k];
    }
    __syncthreads();

    if (tid < NEXP) {
        const int c0 = wcnt[0][tid], c1 = wcnt[1][tid],
                  c2 = wcnt[2][tid], c3 = wcnt[3][tid];
        const int tot = c0 + c1 + c2 + c3;
        int old = 0;
        if (tot) old = atomicAdd(&gcnt[tid * GSTRIDE], tot);
        wbase[0][tid] = old;
        wbase[1][tid] = old + c0;
        wbase[2][tid] = old + c0 + c1;
        wbase[3][tid] = old + c0 + c1 + c2;
    }
    __syncthreads();

    int wb[NEXP], roff[NEXP];
    #pragma unroll
    for (int k = 0; k < NEXP; ++k) { wb[k] = wbase[wv][k]; roff[k] = 0; }

    #pragma unroll
    for (int r = 0; r < ROUNDS; ++r) {
        const int e = (int)((epack >> (r * 8)) & 0xFFu);
        const int n = base + r * 64 + lane;
        int slot = -1;
        #pragma unroll
        for (int k = 0; k < NEXP; ++k) {
            const unsigned long long m = __ballot(e == k);
            if (e == k) slot = wb[k] + roff[k] + (int)__popcll(m & lmask);
            roff[k] += (int)__popcll(m);
        }
        if (e < NEXP)     lists[e * CAP + slot] = n;
        else if (e == 16) out[n] = 0.0f;
    }
}

// ---------------- kernel 2: eval, 1 expert/block, 2 samples/thread ----------------
// Weights staged in LDS (5.4KB/block), read as broadcast ds_read_b128, each read
// amortized over 2 samples. All register indices are macro literals (SROA-proven).
// NS=2 state = h(40) + a(40) + one float4 weight temp + addressing ~= 100 VGPR,
// fits the allocator's 128 cap -> no spill (R6's NS=4 needed ~200 -> spilled).

#define R20(X) X(0) X(1) X(2) X(3) X(4) X(5) X(6) X(7) X(8) X(9) \
               X(10) X(11) X(12) X(13) X(14) X(15) X(16) X(17) X(18) X(19)
#define R5M(X) X(0) X(1) X(2) X(3) X(4)

__global__ __launch_bounds__(256) void eval_kernel(
    const float* __restrict__ x,
    const float* __restrict__ W1, const float* __restrict__ b1,
    const float* __restrict__ W2, const float* __restrict__ b2,
    const float* __restrict__ W3, const float* __restrict__ b3,
    const float* __restrict__ W4, const float* __restrict__ b4,
    const float* __restrict__ W5, const float* __restrict__ b5,
    const int* __restrict__ gcnt, const int* __restrict__ lists,
    float* __restrict__ out)
{
    __shared__ float Wl[EFLOATS];                 // 5.4 KB: one expert

    // j-major: full chunks spread 1-per-CU first; tails are the only doubled CUs
    const int e     = blockIdx.x & 15;            // SGPR-uniform expert id
    const int j     = blockIdx.x >> 4;            // chunk within expert
    const int cbase = j * SPB;
    const int ce    = gcnt[e * GSTRIDE];          // scalar load
    if (cbase >= ce) return;                      // block-uniform early-exit

    const int tid = threadIdx.x;

    // ---- stage this expert's weights into LDS (float4), all threads present ----
    {
        float4*       d4 = reinterpret_cast<float4*>(Wl);
        const float4* s2 = reinterpret_cast<const float4*>(W2 + e * 400);
        const float4* s3 = reinterpret_cast<const float4*>(W3 + e * 400);
        const float4* s4 = reinterpret_cast<const float4*>(W4 + e * 400);
        if (tid < 100) {
            d4[OFF_W2/4 + tid] = s2[tid];
            d4[OFF_W3/4 + tid] = s3[tid];
            d4[OFF_W4/4 + tid] = s4[tid];
        } else if (tid < 110) {
            d4[OFF_W1/4 + (tid-100)] = reinterpret_cast<const float4*>(W1 + e*40)[tid-100];
        } else if (tid < 115) {
            d4[OFF_B1/4 + (tid-110)] = reinterpret_cast<const float4*>(b1 + e*20)[tid-110];
        } else if (tid < 120) {
            d4[OFF_B2/4 + (tid-115)] = reinterpret_cast<const float4*>(b2 + e*20)[tid-115];
        } else if (tid < 125) {
            d4[OFF_B3/4 + (tid-120)] = reinterpret_cast<const float4*>(b3 + e*20)[tid-120];
        } else if (tid < 130) {
            d4[OFF_B4/4 + (tid-125)] = reinterpret_cast<const float4*>(b4 + e*20)[tid-125];
        } else if (tid < 135) {
            d4[OFF_W5/4 + (tid-130)] = reinterpret_cast<const float4*>(W5 + e*20)[tid-130];
        } else if (tid == 135) {
            Wl[OFF_B5] = b5[e];
        }
    }
    __syncthreads();

    // ---- 2 consecutive slots per thread; whole-thread early exit ----
    const int s0 = cbase + tid * NS;
    if (s0 >= ce) return;                         // tail waves retire early

    const int2 iv = *reinterpret_cast<const int2*>(&lists[e * CAP + s0]); // 8B aligned
    const bool v1 = s0 + 1 < ce;
    const int i0 = iv.x;                          // s0 < ce guaranteed valid
    const int i1 = v1 ? iv.y : i0;                // never deref poisoned slots

    const float2* x2p = reinterpret_cast<const float2*>(x);
    const float2 xv0 = x2p[i0], xv1 = x2p[i1];

    float h0[HID], h1[HID];
    float a0[HID], a1[HID];

    // ---- layer 1: 2 -> 20 (broadcast float4 LDS reads) ----
    {
        const float4* w1a = reinterpret_cast<const float4*>(Wl + OFF_W1);
        const float4* w1b = reinterpret_cast<const float4*>(Wl + OFF_W1 + 20);
        const float4* b1f = reinterpret_cast<const float4*>(Wl + OFF_B1);
#define L1E(j, wa, wb, bb) \
        h0[j] = silu(fmaf(xv0.x, wa, fmaf(xv0.y, wb, bb))); \
        h1[j] = silu(fmaf(xv1.x, wa, fmaf(xv1.y, wb, bb)));
#define L1Q(q) { const float4 wa_ = w1a[q], wb_ = w1b[q], bb_ = b1f[q]; \
        L1E(4*q+0, wa_.x, wb_.x, bb_.x) L1E(4*q+1, wa_.y, wb_.y, bb_.y) \
        L1E(4*q+2, wa_.z, wb_.z, bb_.z) L1E(4*q+3, wa_.w, wb_.w, bb_.w) }
        R5M(L1Q)
#undef L1Q
#undef L1E
    }

    // ---- layers 2..4: 20 -> 20; one float4 weight temp live at a time ----
#define BINIT(j, bv) a0[j] = bv; a1[j] = bv;
#define BQ(q)  { const float4 b_ = Bf4[q]; \
        BINIT(4*q+0, b_.x) BINIT(4*q+1, b_.y) BINIT(4*q+2, b_.z) BINIT(4*q+3, b_.w) }
#define QQ(q, J0) { const float4 w_ = Wf4[5*KK + (q)]; \
        a0[(J0)+0] = fmaf(x0_, w_.x, a0[(J0)+0]); a1[(J0)+0] = fmaf(x1_, w_.x, a1[(J0)+0]); \
        a0[(J0)+1] = fmaf(x0_, w_.y, a0[(J0)+1]); a1[(J0)+1] = fmaf(x1_, w_.y, a1[(J0)+1]); \
        a0[(J0)+2] = fmaf(x0_, w_.z, a0[(J0)+2]); a1[(J0)+2] = fmaf(x1_, w_.z, a1[(J0)+2]); \
        a0[(J0)+3] = fmaf(x0_, w_.w, a0[(J0)+3]); a1[(J0)+3] = fmaf(x1_, w_.w, a1[(J0)+3]); }
#define KSTEP(k) { constexpr int KK = (k); \
        const float x0_ = h0[k], x1_ = h1[k]; \
        QQ(0,0) QQ(1,4) QQ(2,8) QQ(3,12) QQ(4,16) }
#define SIL(j) h0[j] = silu(a0[j]); h1[j] = silu(a1[j]);
#define LAYER20(WOFF, BOFF) { \
        const float4* Wf4 = reinterpret_cast<const float4*>(Wl + (WOFF)); \
        const float4* Bf4 = reinterpret_cast<const float4*>(Wl + (BOFF)); \
        R5M(BQ) R20(KSTEP) R20(SIL) }

    LAYER20(OFF_W2, OFF_B2)
    LAYER20(OFF_W3, OFF_B3)
    LAYER20(OFF_W4, OFF_B4)

#undef LAYER20
#undef SIL
#undef KSTEP
#undef QQ
#undef BQ
#undef BINIT

    // ---- layer 5: 20 -> 1 ----
    float o0, o1;
    {
        const float bb = Wl[OFF_B5];
        o0 = bb; o1 = bb;
        const float4* w5f = reinterpret_cast<const float4*>(Wl + OFF_W5);
#define L5E(k, wv) o0 = fmaf(h0[k], wv, o0); o1 = fmaf(h1[k], wv, o1);
#define L5Q(q) { const float4 w_ = w5f[q]; \
        L5E(4*q+0, w_.x) L5E(4*q+1, w_.y) L5E(4*q+2, w_.z) L5E(4*q+3, w_.w) }
        R5M(L5Q)
#undef L5Q
#undef L5E
    }

    out[i0] = o0;                 // s0 valid by construction
    if (v1) out[i1] = o1;
}

extern "C" void kernel_launch(void* const* d_in, const int* in_sizes, int n_in,
                              void* d_out, int out_size, void* d_ws, size_t ws_size,
                              hipStream_t stream) {
    const float* x  = (const float*)d_in[0];
    const float* W1 = (const float*)d_in[1];
    const float* b1 = (const float*)d_in[2];
    const float* W2 = (const float*)d_in[3];
    const float* b2 = (const float*)d_in[4];
    const float* W3 = (const float*)d_in[5];
    const float* b3 = (const float*)d_in[6];
    const float* W4 = (const float*)d_in[7];
    const float* b4 = (const float*)d_in[8];
    const float* W5 = (const float*)d_in[9];
    const float* b5 = (const float*)d_in[10];
    float* out = (float*)d_out;

    const int n_total = in_sizes[0] / 2;          // 262144 samples

    int* gcnt  = (int*)d_ws;                      // 16 counters, 64B apart
    int* lists = (int*)d_ws + NEXP * GSTRIDE;     // 16 x CAP sample indices

    hipMemsetAsync(d_ws, 0, NEXP * GSTRIDE * sizeof(int), stream);

    const int k1_blocks = (n_total + (ROUNDS * 256) - 1) / (ROUNDS * 256); // 256
    hipLaunchKernelGGL(bucket_kernel, dim3(k1_blocks), dim3(256), 0, stream,
                       x, n_total, gcnt, lists, out);

    hipLaunchKernelGGL(eval_kernel, dim3(NEXP * BPE), dim3(256), 0, stream,
                       x, W1, b1, W2, b2, W3, b3, W4, b4, W5, b5,
                       gcnt, lists, out);
}